// Round 1
// baseline (457.792 us; speedup 1.0000x reference)
//
#include <hip/hip_runtime.h>
#include <math.h>

// Problem constants (fixed instance per reference setup_inputs)
#define NB 2
#define C  256
#define H  200
#define W  304
#define PH 7
#define PW 7
#define G  2
#define SPATIAL_SCALE 0.25f

// One block handles 256 of the C*PH*PW=12544 outputs of one ROI.
// idx = c*49 + ph*7 + pw  (cell-fastest => spatial locality within a wave,
// and output writes are 256 consecutive floats => fully coalesced).
__global__ __launch_bounds__(256) void roi_align_rotated_kernel(
    const float* __restrict__ inp, const float* __restrict__ rois,
    float* __restrict__ out)
{
    const int r   = blockIdx.x;
    const int idx = blockIdx.y * 256 + threadIdx.x;   // < C*49 = 12544
    const int c    = idx / 49;
    const int cell = idx - c * 49;
    const int ph   = cell / 7;
    const int pw   = cell - ph * 7;

    // ROI params — wave-uniform (r = blockIdx.x), compiler scalarizes loads.
    const float* rr = rois + r * 6;
    const int   b   = (int)rr[0];
    const float cx  = rr[1] * SPATIAL_SCALE - 0.5f;
    const float cy  = rr[2] * SPATIAL_SCALE - 0.5f;
    const float rw  = rr[3] * SPATIAL_SCALE;
    const float rh  = rr[4] * SPATIAL_SCALE;
    const float th  = rr[5] * (float)(M_PI / 180.0);
    float st, ct;
    sincosf(th, &st, &ct);

    const float bin_h   = rh / (float)PH;
    const float bin_w   = rw / (float)PW;
    const float start_h = -rh * 0.5f;
    const float start_w = -rw * 0.5f;

    const float* __restrict__ plane = inp + (size_t)(b * C + c) * (H * W);

    float acc = 0.0f;
#pragma unroll
    for (int iy = 0; iy < G; ++iy) {
        const float yy = start_h + (float)ph * bin_h
                       + ((float)iy + 0.5f) * bin_h / (float)G;
#pragma unroll
        for (int ix = 0; ix < G; ++ix) {
            const float xx = start_w + (float)pw * bin_w
                           + ((float)ix + 0.5f) * bin_w / (float)G;
            const float y = yy * ct - xx * st + cy;
            const float x = yy * st + xx * ct + cx;

            // validity on UNclipped coords, matching reference
            if (y < -1.0f || y > (float)H || x < -1.0f || x > (float)W)
                continue;

            float yc = fminf(fmaxf(y, 0.0f), (float)(H - 1));
            float xc = fminf(fmaxf(x, 0.0f), (float)(W - 1));
            int yl = (int)floorf(yc);
            int xl = (int)floorf(xc);
            int yh = min(yl + 1, H - 1);
            int xh = min(xl + 1, W - 1);
            const float ly = yc - (float)yl;
            const float lx = xc - (float)xl;
            const float hy = 1.0f - ly;
            const float hx = 1.0f - lx;

            const float v00 = plane[yl * W + xl];
            const float v01 = plane[yl * W + xh];
            const float v10 = plane[yh * W + xl];
            const float v11 = plane[yh * W + xh];

            acc += hy * (hx * v00 + lx * v01) + ly * (hx * v10 + lx * v11);
        }
    }

    out[(size_t)r * (C * PH * PW) + idx] = acc * 0.25f;
}

extern "C" void kernel_launch(void* const* d_in, const int* in_sizes, int n_in,
                              void* d_out, int out_size, void* d_ws, size_t ws_size,
                              hipStream_t stream) {
    const float* inp  = (const float*)d_in[0];
    const float* rois = (const float*)d_in[1];
    float* out = (float*)d_out;

    const int R = in_sizes[1] / 6;              // 1000
    dim3 grid(R, (C * PH * PW + 255) / 256);    // (1000, 49)
    dim3 block(256);
    roi_align_rotated_kernel<<<grid, block, 0, stream>>>(inp, rois, out);
}

// Round 3
// 405.223 us; speedup vs baseline: 1.1297x; 1.1297x over previous
//
#include <hip/hip_runtime.h>
#include <math.h>

// Problem constants (fixed instance per reference setup_inputs)
#define NB 2
#define C  256
#define H  200
#define W  304
#define HW (H * W)                       // 60800 = 1900*32 (exact tiles)
#define PH 7
#define PW 7
#define SPATIAL_SCALE 0.25f
#define NHWC_ELEMS ((size_t)NB * H * W * C)
#define NHWC_BYTES (NHWC_ELEMS * sizeof(float))   // 124,518,400

// ---------------------------------------------------------------------------
// Kernel A: NCHW -> NHWC transpose (per batch: transpose 256 x 60800 matrix).
// 32x32 LDS tile (+1 pad), block (32,8), each thread moves 4 elements.
// Grids are exact: 60800/32=1900, 256/32=8. No guards, no partial tiles.
// ---------------------------------------------------------------------------
__global__ __launch_bounds__(256) void nchw_to_nhwc(
    const float* __restrict__ in, float* __restrict__ out)
{
    __shared__ float tile[32][33];
    const int n  = blockIdx.z;
    const int s0 = blockIdx.x * 32;   // spatial tile origin
    const int c0 = blockIdx.y * 32;   // channel tile origin
    const int tx = threadIdx.x;       // 0..31
    const int ty = threadIdx.y;       // 0..7

    const float* __restrict__ src = in  + (size_t)n * C  * HW;
    float*       __restrict__ dst = out + (size_t)n * HW * C;

#pragma unroll
    for (int i = 0; i < 4; ++i)
        tile[ty + i * 8][tx] = src[(size_t)(c0 + ty + i * 8) * HW + (s0 + tx)];
    __syncthreads();
#pragma unroll
    for (int i = 0; i < 4; ++i)
        dst[(size_t)(s0 + ty + i * 8) * C + (c0 + tx)] = tile[tx][ty + i * 8];
}

// ---------------------------------------------------------------------------
// Kernel B: one block per (roi, pooled cell); thread t = channel t.
// All sample coords/weights are block-uniform (scalarized by compiler);
// every gather is lane-contiguous in channel => fully coalesced.
// 16 independent loads/thread, branchless validity, exact bijective coverage.
// ---------------------------------------------------------------------------
__global__ __launch_bounds__(256) void roi_gather_nhwc(
    const float* __restrict__ nhwc, const float* __restrict__ rois,
    float* __restrict__ out)
{
    const int r    = blockIdx.x;
    const int cell = blockIdx.y;      // 0..48
    const int ph   = cell / 7;
    const int pw   = cell - ph * 7;
    const int c    = threadIdx.x;     // 0..255

    const float* rr = rois + (size_t)r * 6;
    const int   b   = (int)rr[0];
    const float cx  = rr[1] * SPATIAL_SCALE - 0.5f;
    const float cy  = rr[2] * SPATIAL_SCALE - 0.5f;
    const float rw  = rr[3] * SPATIAL_SCALE;
    const float rh  = rr[4] * SPATIAL_SCALE;
    const float th  = rr[5] * (float)(M_PI / 180.0);
    float st, ct;
    sincosf(th, &st, &ct);

    const float bin_h   = rh * (1.0f / PH);
    const float bin_w   = rw * (1.0f / PW);
    const float start_h = -rh * 0.5f;
    const float start_w = -rw * 0.5f;

    float acc = 0.0f;
#pragma unroll
    for (int s = 0; s < 4; ++s) {
        const int iy = s >> 1, ix = s & 1;
        const float yy = start_h + (float)ph * bin_h
                       + ((float)iy + 0.5f) * bin_h * 0.5f;
        const float xx = start_w + (float)pw * bin_w
                       + ((float)ix + 0.5f) * bin_w * 0.5f;
        const float y = yy * ct - xx * st + cy;
        const float x = yy * st + xx * ct + cx;

        // validity on UNclipped coords (reference semantics); fold /4 here
        const bool valid = (y >= -1.0f) && (y <= (float)H)
                        && (x >= -1.0f) && (x <= (float)W);
        const float wv = valid ? 0.25f : 0.0f;

        const float yc = fminf(fmaxf(y, 0.0f), (float)(H - 1));
        const float xc = fminf(fmaxf(x, 0.0f), (float)(W - 1));
        const int yl = (int)floorf(yc);
        const int xl = (int)floorf(xc);
        const int yh = min(yl + 1, H - 1);
        const int xh = min(xl + 1, W - 1);
        const float ly = yc - (float)yl;
        const float lx = xc - (float)xl;
        const float hy = 1.0f - ly;
        const float hx = 1.0f - lx;

        const size_t p00 = ((size_t)(b * H + yl) * W + xl) * C + c;
        const size_t p01 = ((size_t)(b * H + yl) * W + xh) * C + c;
        const size_t p10 = ((size_t)(b * H + yh) * W + xl) * C + c;
        const size_t p11 = ((size_t)(b * H + yh) * W + xh) * C + c;

        acc += wv * (hy * (hx * nhwc[p00] + lx * nhwc[p01])
                   + ly * (hx * nhwc[p10] + lx * nhwc[p11]));
    }

    out[(size_t)r * (C * PH * PW) + (size_t)c * (PH * PW) + cell] = acc;
}

// ---------------------------------------------------------------------------
// Fallback (proven round-1 kernel): used only if ws_size can't hold NHWC.
// idx = c*49 + ph*7 + pw; exact coverage (49*256 = 12544), no guards.
// ---------------------------------------------------------------------------
__global__ __launch_bounds__(256) void roi_align_direct(
    const float* __restrict__ inp, const float* __restrict__ rois,
    float* __restrict__ out)
{
    const int r   = blockIdx.x;
    const int idx = blockIdx.y * 256 + threadIdx.x;   // < 12544
    const int c    = idx / 49;
    const int cell = idx - c * 49;
    const int ph   = cell / 7;
    const int pw   = cell - ph * 7;

    const float* rr = rois + (size_t)r * 6;
    const int   b   = (int)rr[0];
    const float cx  = rr[1] * SPATIAL_SCALE - 0.5f;
    const float cy  = rr[2] * SPATIAL_SCALE - 0.5f;
    const float rw  = rr[3] * SPATIAL_SCALE;
    const float rh  = rr[4] * SPATIAL_SCALE;
    const float th  = rr[5] * (float)(M_PI / 180.0);
    float st, ct;
    sincosf(th, &st, &ct);

    const float bin_h   = rh * (1.0f / PH);
    const float bin_w   = rw * (1.0f / PW);
    const float start_h = -rh * 0.5f;
    const float start_w = -rw * 0.5f;

    const float* __restrict__ plane = inp + (size_t)(b * C + c) * HW;

    float acc = 0.0f;
#pragma unroll
    for (int s = 0; s < 4; ++s) {
        const int iy = s >> 1, ix = s & 1;
        const float yy = start_h + (float)ph * bin_h
                       + ((float)iy + 0.5f) * bin_h * 0.5f;
        const float xx = start_w + (float)pw * bin_w
                       + ((float)ix + 0.5f) * bin_w * 0.5f;
        const float y = yy * ct - xx * st + cy;
        const float x = yy * st + xx * ct + cx;

        const bool valid = (y >= -1.0f) && (y <= (float)H)
                        && (x >= -1.0f) && (x <= (float)W);
        const float wv = valid ? 0.25f : 0.0f;

        const float yc = fminf(fmaxf(y, 0.0f), (float)(H - 1));
        const float xc = fminf(fmaxf(x, 0.0f), (float)(W - 1));
        const int yl = (int)floorf(yc);
        const int xl = (int)floorf(xc);
        const int yh = min(yl + 1, H - 1);
        const int xh = min(xl + 1, W - 1);
        const float ly = yc - (float)yl;
        const float lx = xc - (float)xl;
        const float hy = 1.0f - ly;
        const float hx = 1.0f - lx;

        acc += wv * (hy * (hx * plane[yl * W + xl] + lx * plane[yl * W + xh])
                   + ly * (hx * plane[yh * W + xl] + lx * plane[yh * W + xh]));
    }

    out[(size_t)r * (C * PH * PW) + idx] = acc;
}

extern "C" void kernel_launch(void* const* d_in, const int* in_sizes, int n_in,
                              void* d_out, int out_size, void* d_ws, size_t ws_size,
                              hipStream_t stream) {
    const float* inp  = (const float*)d_in[0];
    const float* rois = (const float*)d_in[1];
    float* out = (float*)d_out;
    const int R = in_sizes[1] / 6;            // 1000

    if (ws_size >= NHWC_BYTES) {
        float* nhwc = (float*)d_ws;
        dim3 gA(HW / 32, C / 32, NB);         // (1900, 8, 2) — exact
        dim3 bA(32, 8, 1);
        nchw_to_nhwc<<<gA, bA, 0, stream>>>(inp, nhwc);

        dim3 gB(R, PH * PW);                  // (1000, 49) — exact
        roi_gather_nhwc<<<gB, 256, 0, stream>>>(nhwc, rois, out);
    } else {
        dim3 grid(R, (C * PH * PW) / 256);    // (1000, 49) — exact
        roi_align_direct<<<grid, 256, 0, stream>>>(inp, rois, out);
    }
}

// Round 4
// 301.174 us; speedup vs baseline: 1.5200x; 1.3455x over previous
//
#include <hip/hip_runtime.h>
#include <math.h>

// Problem constants (fixed instance per reference setup_inputs)
#define NB 2
#define C  256
#define H  200
#define W  304
#define HW (H * W)                       // 60800 = 1900*32 (exact tiles)
#define PH 7
#define PW 7
#define CELLS (PH * PW)                  // 49
#define SPATIAL_SCALE 0.25f
#define NHWC_ELEMS ((size_t)NB * H * W * C)
#define NHWC_BYTES (NHWC_ELEMS * sizeof(float))   // 124,518,400

// ---------------------------------------------------------------------------
// Kernel A: NCHW -> NHWC transpose (per batch: transpose 256 x 60800 matrix).
// 32x32 LDS tile (+1 pad), block (32,8). Exact grids, no guards. (proven R3)
// ---------------------------------------------------------------------------
__global__ __launch_bounds__(256) void nchw_to_nhwc(
    const float* __restrict__ in, float* __restrict__ out)
{
    __shared__ float tile[32][33];
    const int n  = blockIdx.z;
    const int s0 = blockIdx.x * 32;   // spatial tile origin
    const int c0 = blockIdx.y * 32;   // channel tile origin
    const int tx = threadIdx.x;       // 0..31
    const int ty = threadIdx.y;       // 0..7

    const float* __restrict__ src = in  + (size_t)n * C  * HW;
    float*       __restrict__ dst = out + (size_t)n * HW * C;

#pragma unroll
    for (int i = 0; i < 4; ++i)
        tile[ty + i * 8][tx] = src[(size_t)(c0 + ty + i * 8) * HW + (s0 + tx)];
    __syncthreads();
#pragma unroll
    for (int i = 0; i < 4; ++i)
        dst[(size_t)(s0 + ty + i * 8) * C + (c0 + tx)] = tile[tx][ty + i * 8];
}

// ---------------------------------------------------------------------------
// Kernel B (restructured): ONE block per ROI, thread = channel.
//  - all 49 cells computed by the block => L1 reuse of overlapping corners
//  - results staged in LDS sh[c*49+cell] (stride 49, gcd(49,32)=1 => no
//    bank conflicts), then 49 exactly-coalesced 1KB wave stores.
//  - every output cache line is written whole, by one wave => no write amp.
// ---------------------------------------------------------------------------
__global__ __launch_bounds__(256) void roi_gather_nhwc(
    const float* __restrict__ nhwc, const float* __restrict__ rois,
    float* __restrict__ out)
{
    __shared__ float sh[C * CELLS];   // 50176 B
    const int r = blockIdx.x;
    const int c = threadIdx.x;        // channel 0..255

    const float* rr = rois + (size_t)r * 6;
    const int   b   = (int)rr[0];
    const float cx  = rr[1] * SPATIAL_SCALE - 0.5f;
    const float cy  = rr[2] * SPATIAL_SCALE - 0.5f;
    const float rw  = rr[3] * SPATIAL_SCALE;
    const float rh  = rr[4] * SPATIAL_SCALE;
    const float th  = rr[5] * (float)(M_PI / 180.0);
    float st, ct;
    sincosf(th, &st, &ct);

    const float bin_h   = rh * (1.0f / PH);
    const float bin_w   = rw * (1.0f / PW);
    const float start_h = -rh * 0.5f;
    const float start_w = -rw * 0.5f;

    const size_t pixbase = (size_t)b * HW;   // pixel index base for batch b

    for (int cell = 0; cell < CELLS; ++cell) {
        const int ph = cell / 7;
        const int pw = cell - ph * 7;
        float acc = 0.0f;
#pragma unroll
        for (int s = 0; s < 4; ++s) {
            const int iy = s >> 1, ix = s & 1;
            const float yy = start_h + (float)ph * bin_h
                           + ((float)iy + 0.5f) * bin_h * 0.5f;
            const float xx = start_w + (float)pw * bin_w
                           + ((float)ix + 0.5f) * bin_w * 0.5f;
            const float y = yy * ct - xx * st + cy;
            const float x = yy * st + xx * ct + cx;

            // validity on UNclipped coords (reference semantics); fold /4 in
            const bool valid = (y >= -1.0f) && (y <= (float)H)
                            && (x >= -1.0f) && (x <= (float)W);
            const float wv = valid ? 0.25f : 0.0f;

            const float yc = fminf(fmaxf(y, 0.0f), (float)(H - 1));
            const float xc = fminf(fmaxf(x, 0.0f), (float)(W - 1));
            const int yl = (int)floorf(yc);
            const int xl = (int)floorf(xc);
            const int yh = min(yl + 1, H - 1);
            const int xh = min(xl + 1, W - 1);
            const float ly = yc - (float)yl;
            const float lx = xc - (float)xl;
            const float hy = 1.0f - ly;
            const float hx = 1.0f - lx;

            const size_t p00 = (pixbase + (size_t)(yl * W + xl)) * C + c;
            const size_t p01 = (pixbase + (size_t)(yl * W + xh)) * C + c;
            const size_t p10 = (pixbase + (size_t)(yh * W + xl)) * C + c;
            const size_t p11 = (pixbase + (size_t)(yh * W + xh)) * C + c;

            acc += wv * (hy * (hx * nhwc[p00] + lx * nhwc[p01])
                       + ly * (hx * nhwc[p10] + lx * nhwc[p11]));
        }
        sh[c * CELLS + cell] = acc;   // stride 49: bank-conflict-free
    }

    __syncthreads();

    // 12544 = 49 * 256: exactly 49 coalesced 1KB wave stores, no guards.
    const size_t ob = (size_t)r * (C * CELLS);
#pragma unroll
    for (int k = 0; k < CELLS; ++k)
        out[ob + (size_t)k * 256 + c] = sh[k * 256 + c];
}

// ---------------------------------------------------------------------------
// Fallback (proven round-1 kernel): used only if ws_size can't hold NHWC.
// ---------------------------------------------------------------------------
__global__ __launch_bounds__(256) void roi_align_direct(
    const float* __restrict__ inp, const float* __restrict__ rois,
    float* __restrict__ out)
{
    const int r   = blockIdx.x;
    const int idx = blockIdx.y * 256 + threadIdx.x;   // < 12544
    const int c    = idx / 49;
    const int cell = idx - c * 49;
    const int ph   = cell / 7;
    const int pw   = cell - ph * 7;

    const float* rr = rois + (size_t)r * 6;
    const int   b   = (int)rr[0];
    const float cx  = rr[1] * SPATIAL_SCALE - 0.5f;
    const float cy  = rr[2] * SPATIAL_SCALE - 0.5f;
    const float rw  = rr[3] * SPATIAL_SCALE;
    const float rh  = rr[4] * SPATIAL_SCALE;
    const float th  = rr[5] * (float)(M_PI / 180.0);
    float st, ct;
    sincosf(th, &st, &ct);

    const float bin_h   = rh * (1.0f / PH);
    const float bin_w   = rw * (1.0f / PW);
    const float start_h = -rh * 0.5f;
    const float start_w = -rw * 0.5f;

    const float* __restrict__ plane = inp + (size_t)(b * C + c) * HW;

    float acc = 0.0f;
#pragma unroll
    for (int s = 0; s < 4; ++s) {
        const int iy = s >> 1, ix = s & 1;
        const float yy = start_h + (float)ph * bin_h
                       + ((float)iy + 0.5f) * bin_h * 0.5f;
        const float xx = start_w + (float)pw * bin_w
                       + ((float)ix + 0.5f) * bin_w * 0.5f;
        const float y = yy * ct - xx * st + cy;
        const float x = yy * st + xx * ct + cx;

        const bool valid = (y >= -1.0f) && (y <= (float)H)
                        && (x >= -1.0f) && (x <= (float)W);
        const float wv = valid ? 0.25f : 0.0f;

        const float yc = fminf(fmaxf(y, 0.0f), (float)(H - 1));
        const float xc = fminf(fmaxf(x, 0.0f), (float)(W - 1));
        const int yl = (int)floorf(yc);
        const int xl = (int)floorf(xc);
        const int yh = min(yl + 1, H - 1);
        const int xh = min(xl + 1, W - 1);
        const float ly = yc - (float)yl;
        const float lx = xc - (float)xl;
        const float hy = 1.0f - ly;
        const float hx = 1.0f - lx;

        acc += wv * (hy * (hx * plane[yl * W + xl] + lx * plane[yl * W + xh])
                   + ly * (hx * plane[yh * W + xl] + lx * plane[yh * W + xh]));
    }

    out[(size_t)r * (C * PH * PW) + idx] = acc;
}

extern "C" void kernel_launch(void* const* d_in, const int* in_sizes, int n_in,
                              void* d_out, int out_size, void* d_ws, size_t ws_size,
                              hipStream_t stream) {
    const float* inp  = (const float*)d_in[0];
    const float* rois = (const float*)d_in[1];
    float* out = (float*)d_out;
    const int R = in_sizes[1] / 6;            // 1000

    if (ws_size >= NHWC_BYTES) {
        float* nhwc = (float*)d_ws;
        dim3 gA(HW / 32, C / 32, NB);         // (1900, 8, 2) — exact
        dim3 bA(32, 8, 1);
        nchw_to_nhwc<<<gA, bA, 0, stream>>>(inp, nhwc);

        roi_gather_nhwc<<<dim3(R), 256, 0, stream>>>(nhwc, rois, out);
    } else {
        dim3 grid(R, (C * PH * PW) / 256);    // (1000, 49) — exact
        roi_align_direct<<<grid, 256, 0, stream>>>(inp, rois, out);
    }
}

// Round 5
// 293.691 us; speedup vs baseline: 1.5588x; 1.0255x over previous
//
#include <hip/hip_runtime.h>
#include <math.h>

// Problem constants (fixed instance per reference setup_inputs)
#define NB 2
#define C  256
#define H  200
#define W  304
#define HW (H * W)                       // 60800 (divisible by 64)
#define PH 7
#define PW 7
#define CELLS (PH * PW)                  // 49
#define SPATIAL_SCALE 0.25f
#define NHWC_ELEMS ((size_t)NB * H * W * C)
#define NHWC_BYTES (NHWC_ELEMS * sizeof(float))   // 124,518,400
#define SH_STRIDE 257                    // 49*257*4 = 50372 B; bank = (cell+c)%32

// ---------------------------------------------------------------------------
// Kernel A: NCHW -> NHWC transpose, float4 on BOTH global sides.
// 64 channels x 64 spatial tile, block (16,16). Exact grids (60800/64=950,
// 256/64=4). LDS pad 65 (odd): scalar LDS writes/reads are 2-way => free.
// ---------------------------------------------------------------------------
__global__ __launch_bounds__(256) void nchw_to_nhwc(
    const float* __restrict__ in, float* __restrict__ out)
{
    __shared__ float tile[64][65];
    const int n  = blockIdx.z;
    const int s0 = blockIdx.x * 64;   // spatial tile origin
    const int c0 = blockIdx.y * 64;   // channel tile origin
    const int tx = threadIdx.x;       // 0..15
    const int ty = threadIdx.y;       // 0..15

    const float* __restrict__ src = in  + (size_t)n * C  * HW;
    float*       __restrict__ dst = out + (size_t)n * HW * C;

#pragma unroll
    for (int i = 0; i < 4; ++i) {
        const int ch = i * 16 + ty;
        const float4 v = *(const float4*)&src[(size_t)(c0 + ch) * HW + s0 + tx * 4];
        tile[ch][tx * 4 + 0] = v.x;
        tile[ch][tx * 4 + 1] = v.y;
        tile[ch][tx * 4 + 2] = v.z;
        tile[ch][tx * 4 + 3] = v.w;
    }
    __syncthreads();
#pragma unroll
    for (int i = 0; i < 4; ++i) {
        const int sp = i * 16 + ty;
        float4 o;
        o.x = tile[tx * 4 + 0][sp];
        o.y = tile[tx * 4 + 1][sp];
        o.z = tile[tx * 4 + 2][sp];
        o.w = tile[tx * 4 + 3][sp];
        *(float4*)&dst[(size_t)(s0 + sp) * C + c0 + tx * 4] = o;
    }
}

// ---------------------------------------------------------------------------
// Kernel B: ONE block per ROI. 64 lanes x float4 = 256 channels per wave;
// the 4 waves split the 49 cells (cell = w, w+4, ...) so uniform coord math
// is computed once per cell per block (was 4x redundant in R4), and each
// sample needs only 4 dwordx4 loads (1KB coalesced) instead of 16 dwords.
// Staging sh[cell*257 + c]: b128 writes and store-phase reads conflict-free.
// Store: 49 exactly-coalesced 1KB wave rows (proven R4 pattern).
// ---------------------------------------------------------------------------
__global__ __launch_bounds__(256) void roi_gather_nhwc(
    const float* __restrict__ nhwc, const float* __restrict__ rois,
    float* __restrict__ out)
{
    __shared__ float sh[CELLS * SH_STRIDE];   // 50372 B
    const int t    = threadIdx.x;
    const int lane = t & 63;
    const int w    = t >> 6;          // wave id 0..3
    const int r    = blockIdx.x;

    const float* rr = rois + (size_t)r * 6;
    const int   b   = (int)rr[0];
    const float cx  = rr[1] * SPATIAL_SCALE - 0.5f;
    const float cy  = rr[2] * SPATIAL_SCALE - 0.5f;
    const float rw  = rr[3] * SPATIAL_SCALE;
    const float rh  = rr[4] * SPATIAL_SCALE;
    const float th  = rr[5] * (float)(M_PI / 180.0);
    float st, ct;
    sincosf(th, &st, &ct);

    const float bin_h   = rh * (1.0f / PH);
    const float bin_w   = rw * (1.0f / PW);
    const float start_h = -rh * 0.5f;
    const float start_w = -rw * 0.5f;

    // base4 + pix*64 addresses channels [4*lane, 4*lane+4) of pixel pix
    const float4* __restrict__ base4 =
        (const float4*)nhwc + (size_t)b * HW * (C / 4) + lane;

    for (int cell = w; cell < CELLS; cell += 4) {
        const int ph = cell / 7;
        const int pw = cell - ph * 7;
        float4 acc = make_float4(0.f, 0.f, 0.f, 0.f);
#pragma unroll
        for (int s = 0; s < 4; ++s) {
            const int iy = s >> 1, ix = s & 1;
            const float yy = start_h + (float)ph * bin_h
                           + ((float)iy + 0.5f) * bin_h * 0.5f;
            const float xx = start_w + (float)pw * bin_w
                           + ((float)ix + 0.5f) * bin_w * 0.5f;
            const float y = yy * ct - xx * st + cy;
            const float x = yy * st + xx * ct + cx;

            // validity on UNclipped coords (reference semantics); fold /4 in
            const bool valid = (y >= -1.0f) && (y <= (float)H)
                            && (x >= -1.0f) && (x <= (float)W);
            const float wv = valid ? 0.25f : 0.0f;

            const float yc = fminf(fmaxf(y, 0.0f), (float)(H - 1));
            const float xc = fminf(fmaxf(x, 0.0f), (float)(W - 1));
            const int yl = (int)floorf(yc);
            const int xl = (int)floorf(xc);
            const int yh = min(yl + 1, H - 1);
            const int xh = min(xl + 1, W - 1);
            const float ly = yc - (float)yl;
            const float lx = xc - (float)xl;
            const float hy = 1.0f - ly;
            const float hx = 1.0f - lx;

            const float w00 = hy * hx * wv;
            const float w01 = hy * lx * wv;
            const float w10 = ly * hx * wv;
            const float w11 = ly * lx * wv;

            const int q00 = (yl * W + xl) * (C / 4);
            const int q01 = (yl * W + xh) * (C / 4);
            const int q10 = (yh * W + xl) * (C / 4);
            const int q11 = (yh * W + xh) * (C / 4);

            const float4 v00 = base4[q00];
            const float4 v01 = base4[q01];
            const float4 v10 = base4[q10];
            const float4 v11 = base4[q11];

            acc.x = fmaf(w00, v00.x, fmaf(w01, v01.x, fmaf(w10, v10.x, fmaf(w11, v11.x, acc.x))));
            acc.y = fmaf(w00, v00.y, fmaf(w01, v01.y, fmaf(w10, v10.y, fmaf(w11, v11.y, acc.y))));
            acc.z = fmaf(w00, v00.z, fmaf(w01, v01.z, fmaf(w10, v10.z, fmaf(w11, v11.z, acc.z))));
            acc.w = fmaf(w00, v00.w, fmaf(w01, v01.w, fmaf(w10, v10.w, fmaf(w11, v11.w, acc.w))));
        }
        // channels 4*lane..4*lane+3 of this cell; stride-257 keeps banks clean
        *(float4*)&sh[cell * SH_STRIDE + lane * 4] = acc;
    }

    __syncthreads();

    // 12544 = 49 * 256: exactly 49 coalesced 1KB wave stores, no guards.
    const size_t ob = (size_t)r * (C * CELLS);
#pragma unroll 7
    for (int k = 0; k < CELLS; ++k) {
        const int f    = k * 256 + t;     // flat output index = c*49 + cell
        const int c    = f / 49;
        const int cell = f - c * 49;
        out[ob + f] = sh[cell * SH_STRIDE + c];
    }
}

// ---------------------------------------------------------------------------
// Fallback (proven round-1 kernel): used only if ws_size can't hold NHWC.
// ---------------------------------------------------------------------------
__global__ __launch_bounds__(256) void roi_align_direct(
    const float* __restrict__ inp, const float* __restrict__ rois,
    float* __restrict__ out)
{
    const int r   = blockIdx.x;
    const int idx = blockIdx.y * 256 + threadIdx.x;   // < 12544
    const int c    = idx / 49;
    const int cell = idx - c * 49;
    const int ph   = cell / 7;
    const int pw   = cell - ph * 7;

    const float* rr = rois + (size_t)r * 6;
    const int   b   = (int)rr[0];
    const float cx  = rr[1] * SPATIAL_SCALE - 0.5f;
    const float cy  = rr[2] * SPATIAL_SCALE - 0.5f;
    const float rw  = rr[3] * SPATIAL_SCALE;
    const float rh  = rr[4] * SPATIAL_SCALE;
    const float th  = rr[5] * (float)(M_PI / 180.0);
    float st, ct;
    sincosf(th, &st, &ct);

    const float bin_h   = rh * (1.0f / PH);
    const float bin_w   = rw * (1.0f / PW);
    const float start_h = -rh * 0.5f;
    const float start_w = -rw * 0.5f;

    const float* __restrict__ plane = inp + (size_t)(b * C + c) * HW;

    float acc = 0.0f;
#pragma unroll
    for (int s = 0; s < 4; ++s) {
        const int iy = s >> 1, ix = s & 1;
        const float yy = start_h + (float)ph * bin_h
                       + ((float)iy + 0.5f) * bin_h * 0.5f;
        const float xx = start_w + (float)pw * bin_w
                       + ((float)ix + 0.5f) * bin_w * 0.5f;
        const float y = yy * ct - xx * st + cy;
        const float x = yy * st + xx * ct + cx;

        const bool valid = (y >= -1.0f) && (y <= (float)H)
                        && (x >= -1.0f) && (x <= (float)W);
        const float wv = valid ? 0.25f : 0.0f;

        const float yc = fminf(fmaxf(y, 0.0f), (float)(H - 1));
        const float xc = fminf(fmaxf(x, 0.0f), (float)(W - 1));
        const int yl = (int)floorf(yc);
        const int xl = (int)floorf(xc);
        const int yh = min(yl + 1, H - 1);
        const int xh = min(xl + 1, W - 1);
        const float ly = yc - (float)yl;
        const float lx = xc - (float)xl;
        const float hy = 1.0f - ly;
        const float hx = 1.0f - lx;

        acc += wv * (hy * (hx * plane[yl * W + xl] + lx * plane[yl * W + xh])
                   + ly * (hx * plane[yh * W + xl] + lx * plane[yh * W + xh]));
    }

    out[(size_t)r * (C * PH * PW) + idx] = acc;
}

extern "C" void kernel_launch(void* const* d_in, const int* in_sizes, int n_in,
                              void* d_out, int out_size, void* d_ws, size_t ws_size,
                              hipStream_t stream) {
    const float* inp  = (const float*)d_in[0];
    const float* rois = (const float*)d_in[1];
    float* out = (float*)d_out;
    const int R = in_sizes[1] / 6;            // 1000

    if (ws_size >= NHWC_BYTES) {
        float* nhwc = (float*)d_ws;
        dim3 gA(HW / 64, C / 64, NB);         // (950, 4, 2) — exact
        dim3 bA(16, 16, 1);
        nchw_to_nhwc<<<gA, bA, 0, stream>>>(inp, nhwc);

        roi_gather_nhwc<<<dim3(R), 256, 0, stream>>>(nhwc, rois, out);
    } else {
        dim3 grid(R, (C * PH * PW) / 256);    // (1000, 49) — exact
        roi_align_direct<<<grid, 256, 0, stream>>>(inp, rois, out);
    }
}

// Round 6
// 287.113 us; speedup vs baseline: 1.5945x; 1.0229x over previous
//
#include <hip/hip_runtime.h>
#include <math.h>

// Problem constants (fixed instance per reference setup_inputs)
#define NB 2
#define C  256
#define H  200
#define W  304
#define HW (H * W)                       // 60800 (divisible by 32 and 64)
#define PH 7
#define PW 7
#define CELLS (PH * PW)                  // 49
#define SPATIAL_SCALE 0.25f
#define NHWC_ELEMS ((size_t)NB * H * W * C)
#define NHWC_BYTES (NHWC_ELEMS * sizeof(float))   // 124,518,400
#define SH_STRIDE 260                    // row = 1040 B (16B aligned); 49*260*4 = 50960 B

// ---------------------------------------------------------------------------
// Kernel A: NCHW -> NHWC transpose (proven R3/R4 version: scalar 32x33 tile).
// Exact grids: 60800/32=1900, 256/32=8. No guards.
// ---------------------------------------------------------------------------
__global__ __launch_bounds__(256) void nchw_to_nhwc(
    const float* __restrict__ in, float* __restrict__ out)
{
    __shared__ float tile[32][33];
    const int n  = blockIdx.z;
    const int s0 = blockIdx.x * 32;   // spatial tile origin
    const int c0 = blockIdx.y * 32;   // channel tile origin
    const int tx = threadIdx.x;       // 0..31
    const int ty = threadIdx.y;       // 0..7

    const float* __restrict__ src = in  + (size_t)n * C  * HW;
    float*       __restrict__ dst = out + (size_t)n * HW * C;

#pragma unroll
    for (int i = 0; i < 4; ++i)
        tile[ty + i * 8][tx] = src[(size_t)(c0 + ty + i * 8) * HW + (s0 + tx)];
    __syncthreads();
#pragma unroll
    for (int i = 0; i < 4; ++i)
        dst[(size_t)(s0 + ty + i * 8) * C + (c0 + tx)] = tile[tx][ty + i * 8];
}

// ---------------------------------------------------------------------------
// Kernel B: ONE block per ROI; 64 lanes x float4 = 256 channels per wave;
// waves split the 49 cells. NEW in R6: cells processed in PAIRS — all 32
// dwordx4 loads for two cells issued before consumption, so the wave has
// ~32 loads in flight instead of ~4 (R5 was VGPR-starved at VGPR=68 ->
// ~4 serial miss latencies per cell). __launch_bounds__(256,2) caps VGPR
// at 256 (no spill, 2 waves/SIMD; LDS 50.9KB already limits blocks/CU).
// ---------------------------------------------------------------------------
__device__ __forceinline__ void cell_prep(
    int cell, float start_h, float start_w, float bin_h, float bin_w,
    float ct, float st, float cx, float cy,
    int* __restrict__ q, float* __restrict__ wgt)
{
    const int ph = cell / 7;
    const int pw = cell - ph * 7;
#pragma unroll
    for (int s = 0; s < 4; ++s) {
        const int iy = s >> 1, ix = s & 1;
        const float yy = start_h + (float)ph * bin_h
                       + ((float)iy + 0.5f) * bin_h * 0.5f;
        const float xx = start_w + (float)pw * bin_w
                       + ((float)ix + 0.5f) * bin_w * 0.5f;
        const float y = yy * ct - xx * st + cy;
        const float x = yy * st + xx * ct + cx;

        // validity on UNclipped coords (reference semantics); fold /4 in
        const bool valid = (y >= -1.0f) && (y <= (float)H)
                        && (x >= -1.0f) && (x <= (float)W);
        const float wv = valid ? 0.25f : 0.0f;

        const float yc = fminf(fmaxf(y, 0.0f), (float)(H - 1));
        const float xc = fminf(fmaxf(x, 0.0f), (float)(W - 1));
        const int yl = (int)floorf(yc);
        const int xl = (int)floorf(xc);
        const int yh = min(yl + 1, H - 1);
        const int xh = min(xl + 1, W - 1);
        const float ly = yc - (float)yl;
        const float lx = xc - (float)xl;
        const float hy = 1.0f - ly;
        const float hx = 1.0f - lx;

        q[s * 4 + 0] = (yl * W + xl) * (C / 4);
        q[s * 4 + 1] = (yl * W + xh) * (C / 4);
        q[s * 4 + 2] = (yh * W + xl) * (C / 4);
        q[s * 4 + 3] = (yh * W + xh) * (C / 4);
        wgt[s * 4 + 0] = hy * hx * wv;
        wgt[s * 4 + 1] = hy * lx * wv;
        wgt[s * 4 + 2] = ly * hx * wv;
        wgt[s * 4 + 3] = ly * lx * wv;
    }
}

__global__ __launch_bounds__(256, 2) void roi_gather_nhwc(
    const float* __restrict__ nhwc, const float* __restrict__ rois,
    float* __restrict__ out)
{
    __shared__ float sh[CELLS * SH_STRIDE];   // 50960 B
    const int t    = threadIdx.x;
    const int lane = t & 63;
    const int w    = t >> 6;          // wave id 0..3
    const int r    = blockIdx.x;

    const float* rr = rois + (size_t)r * 6;
    const int   b   = (int)rr[0];
    const float cx  = rr[1] * SPATIAL_SCALE - 0.5f;
    const float cy  = rr[2] * SPATIAL_SCALE - 0.5f;
    const float rw  = rr[3] * SPATIAL_SCALE;
    const float rh  = rr[4] * SPATIAL_SCALE;
    const float th  = rr[5] * (float)(M_PI / 180.0);
    float st, ct;
    sincosf(th, &st, &ct);

    const float bin_h   = rh * (1.0f / PH);
    const float bin_w   = rw * (1.0f / PW);
    const float start_h = -rh * 0.5f;
    const float start_w = -rw * 0.5f;

    // base4 + pix*(C/4) addresses channels [4*lane, 4*lane+4) of pixel pix
    const float4* __restrict__ base4 =
        (const float4*)nhwc + (size_t)b * HW * (C / 4) + lane;

    int cell;
    for (cell = w; cell + 4 < CELLS; cell += 8) {
        int   qA[16], qB[16];
        float wA[16], wB[16];
        cell_prep(cell,     start_h, start_w, bin_h, bin_w, ct, st, cx, cy, qA, wA);
        cell_prep(cell + 4, start_h, start_w, bin_h, bin_w, ct, st, cx, cy, qB, wB);

        float4 vA[16], vB[16];
#pragma unroll
        for (int i = 0; i < 16; ++i) vA[i] = base4[qA[i]];
#pragma unroll
        for (int i = 0; i < 16; ++i) vB[i] = base4[qB[i]];

        float4 accA = make_float4(0.f, 0.f, 0.f, 0.f);
        float4 accB = make_float4(0.f, 0.f, 0.f, 0.f);
#pragma unroll
        for (int i = 0; i < 16; ++i) {
            accA.x = fmaf(wA[i], vA[i].x, accA.x);
            accA.y = fmaf(wA[i], vA[i].y, accA.y);
            accA.z = fmaf(wA[i], vA[i].z, accA.z);
            accA.w = fmaf(wA[i], vA[i].w, accA.w);
        }
#pragma unroll
        for (int i = 0; i < 16; ++i) {
            accB.x = fmaf(wB[i], vB[i].x, accB.x);
            accB.y = fmaf(wB[i], vB[i].y, accB.y);
            accB.z = fmaf(wB[i], vB[i].z, accB.z);
            accB.w = fmaf(wB[i], vB[i].w, accB.w);
        }
        *(float4*)&sh[cell       * SH_STRIDE + lane * 4] = accA;
        *(float4*)&sh[(cell + 4) * SH_STRIDE + lane * 4] = accB;
    }
    if (cell < CELLS) {               // leftover (wave 0: cell 48)
        int   qA[16];
        float wA[16];
        cell_prep(cell, start_h, start_w, bin_h, bin_w, ct, st, cx, cy, qA, wA);
        float4 vA[16];
#pragma unroll
        for (int i = 0; i < 16; ++i) vA[i] = base4[qA[i]];
        float4 accA = make_float4(0.f, 0.f, 0.f, 0.f);
#pragma unroll
        for (int i = 0; i < 16; ++i) {
            accA.x = fmaf(wA[i], vA[i].x, accA.x);
            accA.y = fmaf(wA[i], vA[i].y, accA.y);
            accA.z = fmaf(wA[i], vA[i].z, accA.z);
            accA.w = fmaf(wA[i], vA[i].w, accA.w);
        }
        *(float4*)&sh[cell * SH_STRIDE + lane * 4] = accA;
    }

    __syncthreads();

    // 12544 = 49 * 256: exactly 49 coalesced 1KB wave stores, no guards.
    const size_t ob = (size_t)r * (C * CELLS);
#pragma unroll 7
    for (int k = 0; k < CELLS; ++k) {
        const int f    = k * 256 + t;     // flat output index = c*49 + cell
        const int c    = f / 49;
        const int cell2 = f - c * 49;
        out[ob + f] = sh[cell2 * SH_STRIDE + c];
    }
}

// ---------------------------------------------------------------------------
// Fallback (proven round-1 kernel): used only if ws_size can't hold NHWC.
// ---------------------------------------------------------------------------
__global__ __launch_bounds__(256) void roi_align_direct(
    const float* __restrict__ inp, const float* __restrict__ rois,
    float* __restrict__ out)
{
    const int r   = blockIdx.x;
    const int idx = blockIdx.y * 256 + threadIdx.x;   // < 12544
    const int c    = idx / 49;
    const int cell = idx - c * 49;
    const int ph   = cell / 7;
    const int pw   = cell - ph * 7;

    const float* rr = rois + (size_t)r * 6;
    const int   b   = (int)rr[0];
    const float cx  = rr[1] * SPATIAL_SCALE - 0.5f;
    const float cy  = rr[2] * SPATIAL_SCALE - 0.5f;
    const float rw  = rr[3] * SPATIAL_SCALE;
    const float rh  = rr[4] * SPATIAL_SCALE;
    const float th  = rr[5] * (float)(M_PI / 180.0);
    float st, ct;
    sincosf(th, &st, &ct);

    const float bin_h   = rh * (1.0f / PH);
    const float bin_w   = rw * (1.0f / PW);
    const float start_h = -rh * 0.5f;
    const float start_w = -rw * 0.5f;

    const float* __restrict__ plane = inp + (size_t)(b * C + c) * HW;

    float acc = 0.0f;
#pragma unroll
    for (int s = 0; s < 4; ++s) {
        const int iy = s >> 1, ix = s & 1;
        const float yy = start_h + (float)ph * bin_h
                       + ((float)iy + 0.5f) * bin_h * 0.5f;
        const float xx = start_w + (float)pw * bin_w
                       + ((float)ix + 0.5f) * bin_w * 0.5f;
        const float y = yy * ct - xx * st + cy;
        const float x = yy * st + xx * ct + cx;

        const bool valid = (y >= -1.0f) && (y <= (float)H)
                        && (x >= -1.0f) && (x <= (float)W);
        const float wv = valid ? 0.25f : 0.0f;

        const float yc = fminf(fmaxf(y, 0.0f), (float)(H - 1));
        const float xc = fminf(fmaxf(x, 0.0f), (float)(W - 1));
        const int yl = (int)floorf(yc);
        const int xl = (int)floorf(xc);
        const int yh = min(yl + 1, H - 1);
        const int xh = min(xl + 1, W - 1);
        const float ly = yc - (float)yl;
        const float lx = xc - (float)xl;
        const float hy = 1.0f - ly;
        const float hx = 1.0f - lx;

        acc += wv * (hy * (hx * plane[yl * W + xl] + lx * plane[yl * W + xh])
                   + ly * (hx * plane[yh * W + xl] + lx * plane[yh * W + xh]));
    }

    out[(size_t)r * (C * PH * PW) + idx] = acc;
}

extern "C" void kernel_launch(void* const* d_in, const int* in_sizes, int n_in,
                              void* d_out, int out_size, void* d_ws, size_t ws_size,
                              hipStream_t stream) {
    const float* inp  = (const float*)d_in[0];
    const float* rois = (const float*)d_in[1];
    float* out = (float*)d_out;
    const int R = in_sizes[1] / 6;            // 1000

    if (ws_size >= NHWC_BYTES) {
        float* nhwc = (float*)d_ws;
        dim3 gA(HW / 32, C / 32, NB);         // (1900, 8, 2) — exact
        dim3 bA(32, 8, 1);
        nchw_to_nhwc<<<gA, bA, 0, stream>>>(inp, nhwc);

        roi_gather_nhwc<<<dim3(R), 256, 0, stream>>>(nhwc, rois, out);
    } else {
        dim3 grid(R, (C * PH * PW) / 256);    // (1000, 49) — exact
        roi_align_direct<<<grid, 256, 0, stream>>>(inp, rois, out);
    }
}